// Round 1
// baseline (3851.048 us; speedup 1.0000x reference)
//
#include <hip/hip_runtime.h>
#include <math.h>

typedef unsigned short u16;
typedef __bf16 bf16x8 __attribute__((ext_vector_type(8)));
typedef float f32x4 __attribute__((ext_vector_type(4)));

#define NPAD 224
#define NTOK 197
#define NH_ 12
#define E_ 768
#define B_ 32
#define MROWS (B_*NPAD)   // 7168

__device__ __forceinline__ u16 f2bf(float f) {
    union { float f; unsigned u; } x; x.f = f;
    unsigned r = x.u + 0x7fffu + ((x.u >> 16) & 1u);
    return (u16)(r >> 16);
}
__device__ __forceinline__ float bf2f(u16 s) {
    union { unsigned u; float f; } x; x.u = ((unsigned)s) << 16;
    return x.f;
}

// ---------------- generic GEMM: C = A[M,K](bf16) @ Wt[N,K](bf16)^T + bias ----------------
// EPI: 1 = bf16 out; 2 = fp32 out += (residual in-place); 3 = GELU -> bf16 out; 4 = patch-embed scatter (+pos)
template<int EPI>
__global__ __launch_bounds__(256, 2) void gemm_bf16(
    const u16* __restrict__ A, const u16* __restrict__ W,
    const float* __restrict__ bias, void* __restrict__ Cout,
    const float* __restrict__ aux, int M, int N, int K)
{
    __shared__ u16 lds_a[128*32];
    __shared__ u16 lds_b[128*32];
    const int tid = threadIdx.x;
    const int lane = tid & 63;
    const int wm = (tid >> 7);
    const int wn = (tid >> 6) & 1;
    const int m0 = blockIdx.x * 128, n0 = blockIdx.y * 128;
    const int l15 = lane & 15, g8 = (lane >> 4) << 3;
    f32x4 acc[4][4] = {};
    for (int k0 = 0; k0 < K; k0 += 32) {
        #pragma unroll
        for (int it = 0; it < 2; ++it) {
            int flat = it*256 + tid;
            int row = flat >> 2, kb = (flat & 3) << 3;
            *(uint4*)&lds_a[row*32 + kb] = *(const uint4*)&A[(size_t)(m0+row)*K + k0 + kb];
            *(uint4*)&lds_b[row*32 + kb] = *(const uint4*)&W[(size_t)(n0+row)*K + k0 + kb];
        }
        __syncthreads();
        bf16x8 af[4], bfr[4];
        #pragma unroll
        for (int i = 0; i < 4; ++i)
            af[i] = *(const bf16x8*)&lds_a[(wm*64 + i*16 + l15)*32 + g8];
        #pragma unroll
        for (int j = 0; j < 4; ++j)
            bfr[j] = *(const bf16x8*)&lds_b[(wn*64 + j*16 + l15)*32 + g8];
        #pragma unroll
        for (int i = 0; i < 4; ++i)
            #pragma unroll
            for (int j = 0; j < 4; ++j)
                acc[i][j] = __builtin_amdgcn_mfma_f32_16x16x32_bf16(af[i], bfr[j], acc[i][j], 0, 0, 0);
        __syncthreads();
    }
    const int r0 = (lane >> 4) << 2;
    #pragma unroll
    for (int i = 0; i < 4; ++i) {
        #pragma unroll
        for (int j = 0; j < 4; ++j) {
            #pragma unroll
            for (int r = 0; r < 4; ++r) {
                int row = m0 + wm*64 + i*16 + r0 + r;
                int col = n0 + wn*64 + j*16 + l15;
                float v = acc[i][j][r] + bias[col];
                if constexpr (EPI == 1) {
                    ((u16*)Cout)[(size_t)row*N + col] = f2bf(v);
                } else if constexpr (EPI == 2) {
                    ((float*)Cout)[(size_t)row*N + col] += v;
                } else if constexpr (EPI == 3) {
                    float gv = 0.5f * v * (1.0f + erff(v * 0.70710678118f));
                    ((u16*)Cout)[(size_t)row*N + col] = f2bf(gv);
                } else if constexpr (EPI == 4) {
                    int b = row / 196, t = 1 + row % 196;
                    ((float*)Cout)[((size_t)(b*NPAD + t))*E_ + col] = v + aux[(size_t)t*E_ + col];
                }
            }
        }
    }
}

// ---------------- weight transpose+cvt: in[R][C] f32 -> out[C][R] bf16 ----------------
__global__ __launch_bounds__(256) void transpose_w(
    const float* __restrict__ in, u16* __restrict__ out, int R, int C)
{
    __shared__ u16 t[32][33];
    int r0 = blockIdx.x*32, c0 = blockIdx.y*32;
    int tr = threadIdx.x >> 5, tc = threadIdx.x & 31;
    #pragma unroll
    for (int i = 0; i < 4; ++i)
        t[tr + 8*i][tc] = f2bf(in[(size_t)(r0 + tr + 8*i)*C + c0 + tc]);
    __syncthreads();
    #pragma unroll
    for (int i = 0; i < 4; ++i)
        out[(size_t)(c0 + tr + 8*i)*R + r0 + tc] = t[tc][tr + 8*i];
}

// ---------------- fp32 -> bf16 copy (patch_w is already [N][K]) ----------------
__global__ __launch_bounds__(256) void cvt_w(const float* __restrict__ in, u16* __restrict__ out, int n4)
{
    int i = blockIdx.x*256 + threadIdx.x;
    if (i < n4) {
        float4 v = ((const float4*)in)[i];
        unsigned lo = (unsigned)f2bf(v.x) | ((unsigned)f2bf(v.y) << 16);
        unsigned hi = (unsigned)f2bf(v.z) | ((unsigned)f2bf(v.w) << 16);
        ((uint2*)out)[i] = make_uint2(lo, hi);
    }
}

// ---------------- patch gather: x[B,3,224,224] -> Ap[B*196][768] bf16 (k = c*256+p*16+q) ----------------
__global__ __launch_bounds__(192) void gather_patches(const float* __restrict__ x, u16* __restrict__ Ap)
{
    int m = blockIdx.x; int b = m / 196, loc = m % 196;
    int gh = loc / 14, gw = loc % 14;
    int kk = threadIdx.x * 4;
    int c = kk >> 8, rem = kk & 255, p = rem >> 4, q = rem & 15;
    const float* src = &x[(size_t)((b*3 + c)*224 + gh*16 + p)*224 + gw*16 + q];
    float4 v = *(const float4*)src;
    unsigned lo = (unsigned)f2bf(v.x) | ((unsigned)f2bf(v.y) << 16);
    unsigned hi = (unsigned)f2bf(v.z) | ((unsigned)f2bf(v.w) << 16);
    *(uint2*)&Ap[(size_t)m*768 + kk] = make_uint2(lo, hi);
}

// ---------------- X init: row 0 = cls + pos[0]; rows 197..223 = 0 ----------------
__global__ __launch_bounds__(256) void init_x(const float* __restrict__ cls,
                                              const float* __restrict__ pos, float* __restrict__ X)
{
    int b = blockIdx.y, xi = blockIdx.x, tid = threadIdx.x;
    if (xi == 0) {
        #pragma unroll
        for (int i = 0; i < 3; ++i) {
            int e = tid + 256*i;
            X[(size_t)(b*NPAD)*E_ + e] = cls[e] + pos[e];
        }
    } else {
        int t = 196 + xi; // 197..223
        #pragma unroll
        for (int i = 0; i < 3; ++i)
            X[((size_t)(b*NPAD + t))*E_ + tid + 256*i] = 0.0f;
    }
}

// ---------------- LayerNorm rows of X -> bf16 Y (FINAL=1: only row 0 per image -> fp32 d_out) ----------------
template<int FINAL>
__global__ __launch_bounds__(256) void ln_rows(
    const float* __restrict__ X, const float* __restrict__ s,
    const float* __restrict__ bb, void* __restrict__ Y)
{
    int row = FINAL ? blockIdx.x * NPAD : blockIdx.x;
    int t = row % NPAD;
    int tid = threadIdx.x, lane = tid & 63, wave = tid >> 6;
    __shared__ float red[8];
    if (!FINAL && t >= NTOK) {
        u16* yp = (u16*)Y + (size_t)row*E_;
        #pragma unroll
        for (int i = 0; i < 3; ++i) yp[tid + 256*i] = 0;
        return;
    }
    const float* xr = X + (size_t)row*E_;
    float v0 = xr[tid], v1 = xr[tid+256], v2 = xr[tid+512];
    float s1 = v0+v1+v2;
    #pragma unroll
    for (int off = 32; off; off >>= 1) s1 += __shfl_xor(s1, off);
    if (lane == 0) red[wave] = s1;
    __syncthreads();
    float mu = (red[0]+red[1]+red[2]+red[3]) * (1.0f/768.0f);
    float d0 = v0-mu, d1 = v1-mu, d2 = v2-mu;
    float s2 = d0*d0 + d1*d1 + d2*d2;
    #pragma unroll
    for (int off = 32; off; off >>= 1) s2 += __shfl_xor(s2, off);
    if (lane == 0) red[4+wave] = s2;
    __syncthreads();
    float rs = rsqrtf((red[4]+red[5]+red[6]+red[7]) * (1.0f/768.0f) + 1e-6f);
    if (FINAL) {
        float* yp = (float*)Y + (size_t)blockIdx.x*E_;
        yp[tid]     = d0*rs*s[tid]     + bb[tid];
        yp[tid+256] = d1*rs*s[tid+256] + bb[tid+256];
        yp[tid+512] = d2*rs*s[tid+512] + bb[tid+512];
    } else {
        u16* yp = (u16*)Y + (size_t)row*E_;
        yp[tid]     = f2bf(d0*rs*s[tid]     + bb[tid]);
        yp[tid+256] = f2bf(d1*rs*s[tid+256] + bb[tid+256]);
        yp[tid+512] = f2bf(d2*rs*s[tid+512] + bb[tid+512]);
    }
}

// ---------------- attention scores + softmax: P[bh][224][224] bf16 ----------------
__global__ __launch_bounds__(256) void attn_sm(
    const u16* __restrict__ QKV, u16* __restrict__ P)
{
    __shared__ u16 kt[208*64];
    int bh = blockIdx.y, b = bh / NH_, h = bh % NH_;
    int tid = threadIdx.x, lane = tid & 63, wave = tid >> 6;
    const size_t base = (size_t)b * NPAD * 2304;
    for (int it = 0; it < 7; ++it) {
        int flat = it*256 + tid;
        if (flat < 1664) {
            int tok = flat >> 3, ch = (flat & 7) << 3;
            *(uint4*)&kt[tok*64 + ch] =
                *(const uint4*)&QKV[base + (size_t)tok*2304 + 768 + h*64 + ch];
        }
    }
    __syncthreads();
    int i0 = blockIdx.x*64 + wave*16;
    if (i0 >= NPAD) return;
    int l15 = lane & 15, g8 = (lane >> 4) << 3;
    const u16* qp = &QKV[base + (size_t)(i0 + l15)*2304 + h*64];
    bf16x8 q0 = *(const bf16x8*)&qp[g8];
    bf16x8 q1 = *(const bf16x8*)&qp[32 + g8];
    f32x4 c[13];
    #pragma unroll
    for (int jt = 0; jt < 13; ++jt) {
        f32x4 z = {};
        bf16x8 k0 = *(const bf16x8*)&kt[(jt*16 + l15)*64 + g8];
        bf16x8 k1 = *(const bf16x8*)&kt[(jt*16 + l15)*64 + 32 + g8];
        z = __builtin_amdgcn_mfma_f32_16x16x32_bf16(q0, k0, z, 0, 0, 0);
        z = __builtin_amdgcn_mfma_f32_16x16x32_bf16(q1, k1, z, 0, 0, 0);
        c[jt] = z;
    }
    #pragma unroll
    for (int r = 0; r < 4; ++r) {
        float mx = -1e30f;
        #pragma unroll
        for (int jt = 0; jt < 13; ++jt) {
            float v = c[jt][r] * 0.125f;
            if (jt*16 + l15 >= NTOK) v = -1e30f;
            c[jt][r] = v;
            mx = fmaxf(mx, v);
        }
        #pragma unroll
        for (int msk = 1; msk <= 8; msk <<= 1) mx = fmaxf(mx, __shfl_xor(mx, msk));
        float sm = 0.0f;
        #pragma unroll
        for (int jt = 0; jt < 13; ++jt) {
            float e = __expf(c[jt][r] - mx);
            c[jt][r] = e; sm += e;
        }
        #pragma unroll
        for (int msk = 1; msk <= 8; msk <<= 1) sm += __shfl_xor(sm, msk);
        float inv = 1.0f / sm;
        int prow = i0 + (lane >> 4)*4 + r;
        size_t pb = ((size_t)bh*NPAD + prow)*NPAD;
        #pragma unroll
        for (int jt = 0; jt < 13; ++jt)
            P[pb + jt*16 + l15] = f2bf(c[jt][r] * inv);
        P[pb + 208 + l15] = 0;   // zero pad cols 208..223
    }
}

// ---------------- PV: O[b*224+t][h*64+d] bf16 ----------------
__global__ __launch_bounds__(256) void attn_pv(
    const u16* __restrict__ QKV, const u16* __restrict__ P, u16* __restrict__ O)
{
    __shared__ u16 vt[64*232];
    int bh = blockIdx.y, b = bh / NH_, h = bh % NH_;
    int tid = threadIdx.x, lane = tid & 63, wave = tid >> 6;
    const size_t vbase = (size_t)b * NPAD * 2304 + 1536 + h*64;
    int d = tid & 63, grp = tid >> 6;
    for (int it = 0; it < 14; ++it) {
        int tok0 = (it*4 + grp)*4;
        u16 t0 = QKV[vbase + (size_t)(tok0+0)*2304 + d];
        u16 t1 = QKV[vbase + (size_t)(tok0+1)*2304 + d];
        u16 t2 = QKV[vbase + (size_t)(tok0+2)*2304 + d];
        u16 t3 = QKV[vbase + (size_t)(tok0+3)*2304 + d];
        unsigned lo = (unsigned)t0 | ((unsigned)t1 << 16);
        unsigned hi = (unsigned)t2 | ((unsigned)t3 << 16);
        *(uint2*)&vt[d*232 + tok0] = make_uint2(lo, hi);
    }
    __syncthreads();
    int i0 = blockIdx.x*32 + (wave >> 1)*16;
    int d0 = (wave & 1)*32;
    int l15 = lane & 15, g8 = (lane >> 4) << 3;
    f32x4 acc0 = {}, acc1 = {};
    size_t pr = ((size_t)bh*NPAD + i0 + l15)*NPAD;
    #pragma unroll
    for (int kt = 0; kt < 7; ++kt) {
        bf16x8 pa = *(const bf16x8*)&P[pr + kt*32 + g8];
        bf16x8 v0 = *(const bf16x8*)&vt[(d0 + l15)*232 + kt*32 + g8];
        bf16x8 v1 = *(const bf16x8*)&vt[(d0 + 16 + l15)*232 + kt*32 + g8];
        acc0 = __builtin_amdgcn_mfma_f32_16x16x32_bf16(pa, v0, acc0, 0, 0, 0);
        acc1 = __builtin_amdgcn_mfma_f32_16x16x32_bf16(pa, v1, acc1, 0, 0, 0);
    }
    int r0 = (lane >> 4) << 2;
    #pragma unroll
    for (int r = 0; r < 4; ++r) {
        int row = i0 + r0 + r;
        size_t ob = (size_t)(b*NPAD + row)*E_ + h*64;
        O[ob + d0 + l15]      = f2bf(acc0[r]);
        O[ob + d0 + 16 + l15] = f2bf(acc1[r]);
    }
}

// ---------------- head-mean of last-layer P -> d_out attn_back ----------------
__global__ __launch_bounds__(256) void attn_mean(const u16* __restrict__ P, float* __restrict__ out)
{
    int i = blockIdx.x, b = blockIdx.y;
    int j = threadIdx.x;
    if (j >= NTOK) return;
    float s = 0.0f;
    #pragma unroll
    for (int h = 0; h < NH_; ++h)
        s += bf2f(P[((size_t)(b*NH_ + h)*NPAD + i)*NPAD + j]);
    out[24576 + ((size_t)b*NTOK + i)*NTOK + j] = s * (1.0f/12.0f);
}

// ---------------- cls_patch from attn_back ----------------
__global__ __launch_bounds__(256) void cls_patch_k(const float* __restrict__ ab, float* __restrict__ out)
{
    int b = blockIdx.x, tid = threadIdx.x;
    __shared__ float cls[NTOK];
    if (tid < NTOK) cls[tid] = ab[((size_t)b*NTOK + 0)*NTOK + tid];
    __syncthreads();
    if (tid < 196) {
        float s = 0.0f;
        for (int n = 0; n < NTOK; ++n)
            s += ab[((size_t)b*NTOK + n)*NTOK + tid + 1] * cls[n];
        out[1266464 + b*196 + tid] = s * (1.0f/197.0f);
    }
}

extern "C" void kernel_launch(void* const* d_in, const int* in_sizes, int n_in,
                              void* d_out, int out_size, void* d_ws, size_t ws_size,
                              hipStream_t stream) {
    const float* x        = (const float*)d_in[0];
    const float* patch_w  = (const float*)d_in[1];
    const float* patch_b  = (const float*)d_in[2];
    const float* cls_tok  = (const float*)d_in[3];
    const float* pos_emb  = (const float*)d_in[4];
    const float* ln1_s    = (const float*)d_in[5];
    const float* ln1_b    = (const float*)d_in[6];
    const float* qkv_w    = (const float*)d_in[7];
    const float* qkv_b    = (const float*)d_in[8];
    const float* proj_w   = (const float*)d_in[9];
    const float* proj_b   = (const float*)d_in[10];
    const float* ln2_s    = (const float*)d_in[11];
    const float* ln2_b    = (const float*)d_in[12];
    const float* fc1_w    = (const float*)d_in[13];
    const float* fc1_b    = (const float*)d_in[14];
    const float* fc2_w    = (const float*)d_in[15];
    const float* fc2_b    = (const float*)d_in[16];
    const float* lnf_s    = (const float*)d_in[17];
    const float* lnf_b    = (const float*)d_in[18];

    char* w = (char*)d_ws;
    float* X  = (float*)(w);                    // 7168*768*4  = 22,020,096
    u16*   Y  = (u16*)  (w + 22020096);         // 7168*768*2  = 11,010,048
    u16*  QKV = (u16*)  (w + 33030144);         // 7168*2304*2 = 33,030,144
    u16*   P  = (u16*)  (w + 66060288);         // 384*224*224*2 = 38,535,168
    u16*   H  = (u16*)  (w + 104595456);        // 7168*3072*2 = 44,040,192
    u16*   Wt = (u16*)  (w + 148635648);        // up to 3072*768*2 = 4,718,592
    u16*   O  = H;       // alias (disjoint lifetimes)
    u16*   Ap = H;       // alias (embed phase only)
    float* out = (float*)d_out;

    // ---- patch embedding ----
    gather_patches<<<6272, 192, 0, stream>>>(x, Ap);
    cvt_w<<<576, 256, 0, stream>>>(patch_w, Wt, 768*768/4);
    init_x<<<dim3(28, 32), 256, 0, stream>>>(cls_tok, pos_emb, X);
    gemm_bf16<4><<<dim3(49, 6), 256, 0, stream>>>(Ap, Wt, patch_b, X, pos_emb, 6272, 768, 768);

    // ---- 12 transformer blocks ----
    for (int l = 0; l < 12; ++l) {
        ln_rows<0><<<MROWS, 256, 0, stream>>>(X, ln1_s + (size_t)l*768, ln1_b + (size_t)l*768, Y);
        transpose_w<<<dim3(24, 72), 256, 0, stream>>>(qkv_w + (size_t)l*768*2304, Wt, 768, 2304);
        gemm_bf16<1><<<dim3(56, 18), 256, 0, stream>>>(Y, Wt, qkv_b + (size_t)l*2304, QKV, nullptr, MROWS, 2304, 768);
        attn_sm<<<dim3(4, 384), 256, 0, stream>>>(QKV, P);
        attn_pv<<<dim3(7, 384), 256, 0, stream>>>(QKV, P, O);
        transpose_w<<<dim3(24, 24), 256, 0, stream>>>(proj_w + (size_t)l*768*768, Wt, 768, 768);
        gemm_bf16<2><<<dim3(56, 6), 256, 0, stream>>>(O, Wt, proj_b + (size_t)l*768, X, nullptr, MROWS, 768, 768);
        ln_rows<0><<<MROWS, 256, 0, stream>>>(X, ln2_s + (size_t)l*768, ln2_b + (size_t)l*768, Y);
        transpose_w<<<dim3(24, 96), 256, 0, stream>>>(fc1_w + (size_t)l*768*3072, Wt, 768, 3072);
        gemm_bf16<3><<<dim3(56, 24), 256, 0, stream>>>(Y, Wt, fc1_b + (size_t)l*3072, H, nullptr, MROWS, 3072, 768);
        transpose_w<<<dim3(96, 24), 256, 0, stream>>>(fc2_w + (size_t)l*3072*768, Wt, 3072, 768);
        gemm_bf16<2><<<dim3(56, 6), 256, 0, stream>>>(H, Wt, fc2_b + (size_t)l*768, X, nullptr, MROWS, 768, 3072);
    }

    // ---- outputs ----
    attn_mean<<<dim3(197, 32), 256, 0, stream>>>(P, out);
    cls_patch_k<<<32, 256, 0, stream>>>(out + 24576, out);
    ln_rows<1><<<32, 256, 0, stream>>>(X, lnf_s, lnf_b, out);
}

// Round 4
// 3606.156 us; speedup vs baseline: 1.0679x; 1.0679x over previous
//
#include <hip/hip_runtime.h>
#include <math.h>

typedef unsigned short u16;
typedef __bf16 bf16x8 __attribute__((ext_vector_type(8)));
typedef float f32x4 __attribute__((ext_vector_type(4)));

#define NPAD 224
#define NTOK 197
#define NH_ 12
#define E_ 768
#define B_ 32
#define MROWS (B_*NPAD)   // 7168

__device__ __forceinline__ u16 f2bf(float f) {
    union { float f; unsigned u; } x; x.f = f;
    unsigned r = x.u + 0x7fffu + ((x.u >> 16) & 1u);
    return (u16)(r >> 16);
}
__device__ __forceinline__ float bf2f(u16 s) {
    union { unsigned u; float f; } x; x.u = ((unsigned)s) << 16;
    return x.f;
}
__device__ __forceinline__ void gload16(const void* g, void* l) {
    __builtin_amdgcn_global_load_lds((const __attribute__((address_space(1))) void*)g,
                                     (__attribute__((address_space(3))) void*)l, 16, 0, 0);
}

// ---------------- generic GEMM: C = A[M,K](bf16) @ Wt[N,K](bf16)^T + bias ----------------
// m97 structure: 128x128 tile, BK=32, 4 waves, global_load_lds width-16 staging.
// EPI: 1 = bf16 out; 2 = fp32 out += (residual in-place); 3 = GELU -> bf16 out; 4 = patch-embed scatter (+pos)
template<int EPI>
__global__ __launch_bounds__(256, 2) void gemm_bf16(
    const u16* __restrict__ A, const u16* __restrict__ W,
    const float* __restrict__ bias, void* __restrict__ Cout,
    const float* __restrict__ aux, int M, int N, int K)
{
    __shared__ u16 lds_a[128*32];
    __shared__ u16 lds_b[128*32];
    const int tid = threadIdx.x;
    const int lane = tid & 63;
    const int wid = tid >> 6;           // 0..3
    const int wm = wid >> 1, wn = wid & 1;
    const int m0 = blockIdx.x * 128, n0 = blockIdx.y * 128;
    const int l15 = lane & 15, g8 = (lane >> 4) << 3;
    const int srow = lane >> 2;         // 0..15
    const int scol = (lane & 3) << 3;   // 0,8,16,24
    // per-lane global sources (wave w stages rows w*32 .. w*32+31 of each tile)
    const u16* gA = &A[(size_t)(m0 + wid*32 + srow)*K + scol];
    const u16* gB = &W[(size_t)(n0 + wid*32 + srow)*K + scol];
    // wave-uniform LDS destinations (linear: lane*16B)
    u16* dA = &lds_a[wid*32*32];
    u16* dB = &lds_b[wid*32*32];
    f32x4 acc[4][4] = {};
    for (int k0 = 0; k0 < K; k0 += 32) {
        gload16(gA,        dA);
        gload16(gA + 16*K, dA + 512);
        gload16(gB,        dB);
        gload16(gB + 16*K, dB + 512);
        gA += 32; gB += 32;
        __syncthreads();
        bf16x8 af[4], bfr[4];
        #pragma unroll
        for (int i = 0; i < 4; ++i)
            af[i] = *(const bf16x8*)&lds_a[(wm*64 + i*16 + l15)*32 + g8];
        #pragma unroll
        for (int j = 0; j < 4; ++j)
            bfr[j] = *(const bf16x8*)&lds_b[(wn*64 + j*16 + l15)*32 + g8];
        #pragma unroll
        for (int i = 0; i < 4; ++i)
            #pragma unroll
            for (int j = 0; j < 4; ++j)
                acc[i][j] = __builtin_amdgcn_mfma_f32_16x16x32_bf16(af[i], bfr[j], acc[i][j], 0, 0, 0);
        __syncthreads();
    }
    const int r0 = (lane >> 4) << 2;
    #pragma unroll
    for (int i = 0; i < 4; ++i) {
        #pragma unroll
        for (int j = 0; j < 4; ++j) {
            #pragma unroll
            for (int r = 0; r < 4; ++r) {
                int row = m0 + wm*64 + i*16 + r0 + r;
                int col = n0 + wn*64 + j*16 + l15;
                float v = acc[i][j][r] + bias[col];
                if constexpr (EPI == 1) {
                    ((u16*)Cout)[(size_t)row*N + col] = f2bf(v);
                } else if constexpr (EPI == 2) {
                    ((float*)Cout)[(size_t)row*N + col] += v;
                } else if constexpr (EPI == 3) {
                    float gv = 0.5f * v * (1.0f + erff(v * 0.70710678118f));
                    ((u16*)Cout)[(size_t)row*N + col] = f2bf(gv);
                } else if constexpr (EPI == 4) {
                    int b = row / 196, t = 1 + row % 196;
                    ((float*)Cout)[((size_t)(b*NPAD + t))*E_ + col] = v + aux[(size_t)t*E_ + col];
                }
            }
        }
    }
}

// ---------------- fused per-layer weight transpose: all 4 weights -> Wt arena ----------------
// Wt element offsets: qkv_t 0 [2304][768]; proj_t 1769472 [768][768];
//                     fc1_t 2359296 [3072][768]; fc2_t 4718592 [768][3072]
__global__ __launch_bounds__(256) void trans_all(
    const float* __restrict__ qkv_w, const float* __restrict__ proj_w,
    const float* __restrict__ fc1_w, const float* __restrict__ fc2_w,
    u16* __restrict__ Wt)
{
    __shared__ u16 t[32][33];
    int id = blockIdx.x;
    const float* in; u16* out; int R, C, lid;
    if (id < 1728)      { in = qkv_w;  out = Wt;           R = 768;  C = 2304; lid = id; }
    else if (id < 2304) { in = proj_w; out = Wt + 1769472; R = 768;  C = 768;  lid = id - 1728; }
    else if (id < 4608) { in = fc1_w;  out = Wt + 2359296; R = 768;  C = 3072; lid = id - 2304; }
    else                { in = fc2_w;  out = Wt + 4718592; R = 3072; C = 768;  lid = id - 4608; }
    int nR = R >> 5;
    int r0 = (lid % nR) << 5, c0 = (lid / nR) << 5;
    int tr = threadIdx.x >> 5, tc = threadIdx.x & 31;
    #pragma unroll
    for (int i = 0; i < 4; ++i)
        t[tr + 8*i][tc] = f2bf(in[(size_t)(r0 + tr + 8*i)*C + c0 + tc]);
    __syncthreads();
    #pragma unroll
    for (int i = 0; i < 4; ++i)
        out[(size_t)(c0 + tr + 8*i)*R + r0 + tc] = t[tc][tr + 8*i];
}

// ---------------- fp32 -> bf16 copy (patch_w is already [N][K]) ----------------
__global__ __launch_bounds__(256) void cvt_w(const float* __restrict__ in, u16* __restrict__ out, int n4)
{
    int i = blockIdx.x*256 + threadIdx.x;
    if (i < n4) {
        float4 v = ((const float4*)in)[i];
        unsigned lo = (unsigned)f2bf(v.x) | ((unsigned)f2bf(v.y) << 16);
        unsigned hi = (unsigned)f2bf(v.z) | ((unsigned)f2bf(v.w) << 16);
        ((uint2*)out)[i] = make_uint2(lo, hi);
    }
}

// ---------------- patch gather: x[B,3,224,224] -> Ap[B*196][768] bf16 (k = c*256+p*16+q) ----------------
__global__ __launch_bounds__(192) void gather_patches(const float* __restrict__ x, u16* __restrict__ Ap)
{
    int m = blockIdx.x; int b = m / 196, loc = m % 196;
    int gh = loc / 14, gw = loc % 14;
    int kk = threadIdx.x * 4;
    int c = kk >> 8, rem = kk & 255, p = rem >> 4, q = rem & 15;
    const float* src = &x[(size_t)((b*3 + c)*224 + gh*16 + p)*224 + gw*16 + q];
    float4 v = *(const float4*)src;
    unsigned lo = (unsigned)f2bf(v.x) | ((unsigned)f2bf(v.y) << 16);
    unsigned hi = (unsigned)f2bf(v.z) | ((unsigned)f2bf(v.w) << 16);
    *(uint2*)&Ap[(size_t)m*768 + kk] = make_uint2(lo, hi);
}

// ---------------- X init: row 0 = cls + pos[0]; rows 197..223 = 0 ----------------
__global__ __launch_bounds__(256) void init_x(const float* __restrict__ cls,
                                              const float* __restrict__ pos, float* __restrict__ X)
{
    int b = blockIdx.y, xi = blockIdx.x, tid = threadIdx.x;
    if (xi == 0) {
        #pragma unroll
        for (int i = 0; i < 3; ++i) {
            int e = tid + 256*i;
            X[(size_t)(b*NPAD)*E_ + e] = cls[e] + pos[e];
        }
    } else {
        int t = 196 + xi; // 197..223
        #pragma unroll
        for (int i = 0; i < 3; ++i)
            X[((size_t)(b*NPAD + t))*E_ + tid + 256*i] = 0.0f;
    }
}

// ---------------- LayerNorm: one wave per row; FINAL=1: rows b*NPAD -> fp32 d_out ----------------
template<int FINAL>
__global__ __launch_bounds__(256) void ln_rows(
    const float* __restrict__ X, const float* __restrict__ s,
    const float* __restrict__ bb, void* __restrict__ Y)
{
    const int lane = threadIdx.x & 63, wv = threadIdx.x >> 6;
    const int r = blockIdx.x*4 + wv;
    const int row = FINAL ? r*NPAD : r;
    if (!FINAL && (row % NPAD) >= NTOK) {
        uint2* yp = (uint2*)((u16*)Y + (size_t)row*E_);
        uint2 z = make_uint2(0u, 0u);
        yp[lane] = z; yp[lane+64] = z; yp[lane+128] = z;
        return;
    }
    const float4* xr = (const float4*)(X + (size_t)row*E_);
    float4 a0 = xr[lane], a1 = xr[lane+64], a2 = xr[lane+128];
    float s1 = a0.x+a0.y+a0.z+a0.w + a1.x+a1.y+a1.z+a1.w + a2.x+a2.y+a2.z+a2.w;
    #pragma unroll
    for (int off = 32; off; off >>= 1) s1 += __shfl_xor(s1, off);
    float mu = s1 * (1.0f/768.0f);
    float d0x=a0.x-mu, d0y=a0.y-mu, d0z=a0.z-mu, d0w=a0.w-mu;
    float d1x=a1.x-mu, d1y=a1.y-mu, d1z=a1.z-mu, d1w=a1.w-mu;
    float d2x=a2.x-mu, d2y=a2.y-mu, d2z=a2.z-mu, d2w=a2.w-mu;
    float s2 = d0x*d0x+d0y*d0y+d0z*d0z+d0w*d0w
             + d1x*d1x+d1y*d1y+d1z*d1z+d1w*d1w
             + d2x*d2x+d2y*d2y+d2z*d2z+d2w*d2w;
    #pragma unroll
    for (int off = 32; off; off >>= 1) s2 += __shfl_xor(s2, off);
    float rs = rsqrtf(s2 * (1.0f/768.0f) + 1e-6f);
    const float4* sp = (const float4*)s;
    const float4* bp = (const float4*)bb;
    float4 s0v = sp[lane], s1v = sp[lane+64], s2v = sp[lane+128];
    float4 b0v = bp[lane], b1v = bp[lane+64], b2v = bp[lane+128];
    float o0x=d0x*rs*s0v.x+b0v.x, o0y=d0y*rs*s0v.y+b0v.y, o0z=d0z*rs*s0v.z+b0v.z, o0w=d0w*rs*s0v.w+b0v.w;
    float o1x=d1x*rs*s1v.x+b1v.x, o1y=d1y*rs*s1v.y+b1v.y, o1z=d1z*rs*s1v.z+b1v.z, o1w=d1w*rs*s1v.w+b1v.w;
    float o2x=d2x*rs*s2v.x+b2v.x, o2y=d2y*rs*s2v.y+b2v.y, o2z=d2z*rs*s2v.z+b2v.z, o2w=d2w*rs*s2v.w+b2v.w;
    if (FINAL) {
        float4* yp = (float4*)((float*)Y + (size_t)r*E_);
        yp[lane]     = make_float4(o0x,o0y,o0z,o0w);
        yp[lane+64]  = make_float4(o1x,o1y,o1z,o1w);
        yp[lane+128] = make_float4(o2x,o2y,o2z,o2w);
    } else {
        uint2* yp = (uint2*)((u16*)Y + (size_t)row*E_);
        yp[lane]     = make_uint2((unsigned)f2bf(o0x) | ((unsigned)f2bf(o0y)<<16),
                                  (unsigned)f2bf(o0z) | ((unsigned)f2bf(o0w)<<16));
        yp[lane+64]  = make_uint2((unsigned)f2bf(o1x) | ((unsigned)f2bf(o1y)<<16),
                                  (unsigned)f2bf(o1z) | ((unsigned)f2bf(o1w)<<16));
        yp[lane+128] = make_uint2((unsigned)f2bf(o2x) | ((unsigned)f2bf(o2y)<<16),
                                  (unsigned)f2bf(o2z) | ((unsigned)f2bf(o2w)<<16));
    }
}

// ---------------- attention scores + softmax: P[bh][224][224] bf16 ----------------
__global__ __launch_bounds__(256) void attn_sm(
    const u16* __restrict__ QKV, u16* __restrict__ P)
{
    __shared__ u16 kt[208*64];
    int bh = blockIdx.y, b = bh / NH_, h = bh % NH_;
    int tid = threadIdx.x, lane = tid & 63, wave = tid >> 6;
    const size_t base = (size_t)b * NPAD * 2304;
    for (int it = 0; it < 7; ++it) {
        int flat = it*256 + tid;
        if (flat < 1664) {
            int tok = flat >> 3, ch = (flat & 7) << 3;
            *(uint4*)&kt[tok*64 + ch] =
                *(const uint4*)&QKV[base + (size_t)tok*2304 + 768 + h*64 + ch];
        }
    }
    __syncthreads();
    int i0 = blockIdx.x*64 + wave*16;
    if (i0 >= NPAD) return;
    int l15 = lane & 15, g8 = (lane >> 4) << 3;
    const u16* qp = &QKV[base + (size_t)(i0 + l15)*2304 + h*64];
    bf16x8 q0 = *(const bf16x8*)&qp[g8];
    bf16x8 q1 = *(const bf16x8*)&qp[32 + g8];
    f32x4 c[13];
    #pragma unroll
    for (int jt = 0; jt < 13; ++jt) {
        f32x4 z = {};
        bf16x8 k0 = *(const bf16x8*)&kt[(jt*16 + l15)*64 + g8];
        bf16x8 k1 = *(const bf16x8*)&kt[(jt*16 + l15)*64 + 32 + g8];
        z = __builtin_amdgcn_mfma_f32_16x16x32_bf16(q0, k0, z, 0, 0, 0);
        z = __builtin_amdgcn_mfma_f32_16x16x32_bf16(q1, k1, z, 0, 0, 0);
        c[jt] = z;
    }
    #pragma unroll
    for (int r = 0; r < 4; ++r) {
        float mx = -1e30f;
        #pragma unroll
        for (int jt = 0; jt < 13; ++jt) {
            float v = c[jt][r] * 0.125f;
            if (jt*16 + l15 >= NTOK) v = -1e30f;
            c[jt][r] = v;
            mx = fmaxf(mx, v);
        }
        #pragma unroll
        for (int msk = 1; msk <= 8; msk <<= 1) mx = fmaxf(mx, __shfl_xor(mx, msk));
        float sm = 0.0f;
        #pragma unroll
        for (int jt = 0; jt < 13; ++jt) {
            float e = __expf(c[jt][r] - mx);
            c[jt][r] = e; sm += e;
        }
        #pragma unroll
        for (int msk = 1; msk <= 8; msk <<= 1) sm += __shfl_xor(sm, msk);
        float inv = 1.0f / sm;
        int prow = i0 + (lane >> 4)*4 + r;
        size_t pb = ((size_t)bh*NPAD + prow)*NPAD;
        #pragma unroll
        for (int jt = 0; jt < 13; ++jt)
            P[pb + jt*16 + l15] = f2bf(c[jt][r] * inv);
        P[pb + 208 + l15] = 0;   // zero pad cols 208..223
    }
}

// ---------------- PV: O[b*224+t][h*64+d] bf16 ----------------
__global__ __launch_bounds__(256) void attn_pv(
    const u16* __restrict__ QKV, const u16* __restrict__ P, u16* __restrict__ O)
{
    __shared__ u16 vt[64*232];
    int bh = blockIdx.y, b = bh / NH_, h = bh % NH_;
    int tid = threadIdx.x, lane = tid & 63, wave = tid >> 6;
    const size_t vbase = (size_t)b * NPAD * 2304 + 1536 + h*64;
    int d = tid & 63, grp = tid >> 6;
    for (int it = 0; it < 14; ++it) {
        int tok0 = (it*4 + grp)*4;
        u16 t0 = QKV[vbase + (size_t)(tok0+0)*2304 + d];
        u16 t1 = QKV[vbase + (size_t)(tok0+1)*2304 + d];
        u16 t2 = QKV[vbase + (size_t)(tok0+2)*2304 + d];
        u16 t3 = QKV[vbase + (size_t)(tok0+3)*2304 + d];
        unsigned lo = (unsigned)t0 | ((unsigned)t1 << 16);
        unsigned hi = (unsigned)t2 | ((unsigned)t3 << 16);
        *(uint2*)&vt[d*232 + tok0] = make_uint2(lo, hi);
    }
    __syncthreads();
    int i0 = blockIdx.x*32 + (wave >> 1)*16;
    int d0 = (wave & 1)*32;
    int l15 = lane & 15, g8 = (lane >> 4) << 3;
    f32x4 acc0 = {}, acc1 = {};
    size_t pr = ((size_t)bh*NPAD + i0 + l15)*NPAD;
    #pragma unroll
    for (int kt = 0; kt < 7; ++kt) {
        bf16x8 pa = *(const bf16x8*)&P[pr + kt*32 + g8];
        bf16x8 v0 = *(const bf16x8*)&vt[(d0 + l15)*232 + kt*32 + g8];
        bf16x8 v1 = *(const bf16x8*)&vt[(d0 + 16 + l15)*232 + kt*32 + g8];
        acc0 = __builtin_amdgcn_mfma_f32_16x16x32_bf16(pa, v0, acc0, 0, 0, 0);
        acc1 = __builtin_amdgcn_mfma_f32_16x16x32_bf16(pa, v1, acc1, 0, 0, 0);
    }
    int r0 = (lane >> 4) << 2;
    #pragma unroll
    for (int r = 0; r < 4; ++r) {
        int row = i0 + r0 + r;
        size_t ob = (size_t)(b*NPAD + row)*E_ + h*64;
        O[ob + d0 + l15]      = f2bf(acc0[r]);
        O[ob + d0 + 16 + l15] = f2bf(acc1[r]);
    }
}

// ---------------- head-mean of last-layer P -> d_out attn_back ----------------
__global__ __launch_bounds__(256) void attn_mean(const u16* __restrict__ P, float* __restrict__ out)
{
    int i = blockIdx.x, b = blockIdx.y;
    int j = threadIdx.x;
    if (j >= NTOK) return;
    float s = 0.0f;
    #pragma unroll
    for (int h = 0; h < NH_; ++h)
        s += bf2f(P[((size_t)(b*NH_ + h)*NPAD + i)*NPAD + j]);
    out[24576 + ((size_t)b*NTOK + i)*NTOK + j] = s * (1.0f/12.0f);
}

// ---------------- cls_patch from attn_back ----------------
__global__ __launch_bounds__(256) void cls_patch_k(const float* __restrict__ ab, float* __restrict__ out)
{
    int b = blockIdx.x, tid = threadIdx.x;
    __shared__ float cls[NTOK];
    if (tid < NTOK) cls[tid] = ab[((size_t)b*NTOK + 0)*NTOK + tid];
    __syncthreads();
    if (tid < 196) {
        float s = 0.0f;
        for (int n = 0; n < NTOK; ++n)
            s += ab[((size_t)b*NTOK + n)*NTOK + tid + 1] * cls[n];
        out[1266464 + b*196 + tid] = s * (1.0f/197.0f);
    }
}

extern "C" void kernel_launch(void* const* d_in, const int* in_sizes, int n_in,
                              void* d_out, int out_size, void* d_ws, size_t ws_size,
                              hipStream_t stream) {
    const float* x        = (const float*)d_in[0];
    const float* patch_w  = (const float*)d_in[1];
    const float* patch_b  = (const float*)d_in[2];
    const float* cls_tok  = (const float*)d_in[3];
    const float* pos_emb  = (const float*)d_in[4];
    const float* ln1_s    = (const float*)d_in[5];
    const float* ln1_b    = (const float*)d_in[6];
    const float* qkv_w    = (const float*)d_in[7];
    const float* qkv_b    = (const float*)d_in[8];
    const float* proj_w   = (const float*)d_in[9];
    const float* proj_b   = (const float*)d_in[10];
    const float* ln2_s    = (const float*)d_in[11];
    const float* ln2_b    = (const float*)d_in[12];
    const float* fc1_w    = (const float*)d_in[13];
    const float* fc1_b    = (const float*)d_in[14];
    const float* fc2_w    = (const float*)d_in[15];
    const float* fc2_b    = (const float*)d_in[16];
    const float* lnf_s    = (const float*)d_in[17];
    const float* lnf_b    = (const float*)d_in[18];

    char* w = (char*)d_ws;
    float* X  = (float*)(w);                    // 22,020,096
    u16*   Y  = (u16*)  (w + 22020096);         // 11,010,048
    u16*  QKV = (u16*)  (w + 33030144);         // 33,030,144
    u16*   P  = (u16*)  (w + 66060288);         // 38,535,168
    u16*   H  = (u16*)  (w + 104595456);        // 44,040,192
    u16*   Wt = (u16*)  (w + 148635648);        // 14,155,776 (4 transposed weights)
    u16*   O  = H;       // alias (disjoint lifetimes)
    u16*   Ap = H;       // alias (embed phase only)
    float* out = (float*)d_out;

    // ---- patch embedding ----
    gather_patches<<<6272, 192, 0, stream>>>(x, Ap);
    cvt_w<<<576, 256, 0, stream>>>(patch_w, Wt, 768*768/4);
    init_x<<<dim3(28, 32), 256, 0, stream>>>(cls_tok, pos_emb, X);
    gemm_bf16<4><<<dim3(49, 6), 256, 0, stream>>>(Ap, Wt, patch_b, X, pos_emb, 6272, 768, 768);

    // ---- 12 transformer blocks ----
    for (int l = 0; l < 12; ++l) {
        trans_all<<<6912, 256, 0, stream>>>(qkv_w + (size_t)l*1769472, proj_w + (size_t)l*589824,
                                            fc1_w + (size_t)l*2359296, fc2_w + (size_t)l*2359296, Wt);
        ln_rows<0><<<1792, 256, 0, stream>>>(X, ln1_s + (size_t)l*768, ln1_b + (size_t)l*768, Y);
        gemm_bf16<1><<<dim3(56, 18), 256, 0, stream>>>(Y, Wt, qkv_b + (size_t)l*2304, QKV, nullptr, MROWS, 2304, 768);
        attn_sm<<<dim3(4, 384), 256, 0, stream>>>(QKV, P);
        attn_pv<<<dim3(7, 384), 256, 0, stream>>>(QKV, P, O);
        gemm_bf16<2><<<dim3(56, 6), 256, 0, stream>>>(O, Wt + 1769472, proj_b + (size_t)l*768, X, nullptr, MROWS, 768, 768);
        ln_rows<0><<<1792, 256, 0, stream>>>(X, ln2_s + (size_t)l*768, ln2_b + (size_t)l*768, Y);
        gemm_bf16<3><<<dim3(56, 24), 256, 0, stream>>>(Y, Wt + 2359296, fc1_b + (size_t)l*3072, H, nullptr, MROWS, 3072, 768);
        gemm_bf16<2><<<dim3(56, 6), 256, 0, stream>>>(H, Wt + 4718592, fc2_b + (size_t)l*768, X, nullptr, MROWS, 768, 3072);
    }

    // ---- outputs ----
    attn_mean<<<dim3(197, 32), 256, 0, stream>>>(P, out);
    cls_patch_k<<<32, 256, 0, stream>>>(out + 24576, out);
    ln_rows<1><<<8, 256, 0, stream>>>(X, lnf_s, lnf_b, out);
}